// Round 3
// baseline (166.452 us; speedup 1.0000x reference)
//
#include <hip/hip_runtime.h>

#define EPS 1e-7f

constexpr int B   = 16;
constexpr int N   = 512 * 1024;        // elements per batch (C=1)
constexpr int N4  = N / 4;             // float4 per batch = 131072
constexpr int TPB = 256;               // threads per block
constexpr int BPB = 128;               // blocks per batch
constexpr int TPBATCH = TPB * BPB;     // threads covering one batch = 32768
constexpr int ITERS   = N4 / TPBATCH;  // 4 — compile-time, fully unrolled

typedef float fvec4 __attribute__((ext_vector_type(4)));  // clang-native, OK for nontemporal builtins

// ws layout:
//   ws1: [B*BPB][8] doubles  — per-block partials: Sx,Sx2,Ss,Ss2,Sxs,Sf,Sxf,(pad)
//   ws2: [B*BPB]    doubles  — per-block KLD partials
constexpr size_t WS1_DOUBLES = (size_t)B * BPB * 8;

__device__ __forceinline__ float wave_red_f(float v) {
    #pragma unroll
    for (int o = 32; o > 0; o >>= 1) v += __shfl_down(v, o, 64);
    return v;
}
__device__ __forceinline__ double wave_red_d(double v) {
    #pragma unroll
    for (int o = 32; o > 0; o >>= 1) v += __shfl_down(v, o, 64);
    return v;
}

__global__ __launch_bounds__(TPB) void pass1_kernel(
    const float* __restrict__ inp, const float* __restrict__ sal,
    const float* __restrict__ fix, const float* __restrict__ wgt,
    double* __restrict__ ws1) {
    const int b = blockIdx.y;
    const fvec4* ip = (const fvec4*)(inp + (size_t)b * N);
    const fvec4* sp = (const fvec4*)(sal + (size_t)b * N);
    const fvec4* fp = (const fvec4*)(fix + (size_t)b * N);
    const fvec4* wp = (const fvec4*)wgt;

    const int g = blockIdx.x * TPB + threadIdx.x;   // [0, TPBATCH)

    // Stage ALL loads first: 16 x dwordx4 in flight per lane (max MLP).
    fvec4 vi[ITERS], vs[ITERS], vf[ITERS], vw[ITERS];
    #pragma unroll
    for (int j = 0; j < ITERS; j++) {
        const int i = g + j * TPBATCH;
        vi[j] = ip[i];
        vs[j] = sp[i];
        vf[j] = __builtin_nontemporal_load(&fp[i]);  // fix is read exactly once
        vw[j] = wp[i];
    }

    float sx = 0.f, sx2 = 0.f, ss = 0.f, ss2 = 0.f, sxs = 0.f, sf = 0.f, sxf = 0.f;
    #pragma unroll
    for (int j = 0; j < ITERS; j++) {
        #pragma unroll
        for (int k = 0; k < 4; k++) {
            const float x = vi[j][k] * vw[j][k];
            const float s = vs[j][k] * vw[j][k];
            const float f = vf[j][k] * vw[j][k];
            sx  += x;      sx2 += x * x;
            ss  += s;      ss2 += s * s;
            sxs += x * s;
            sf  += f;      sxf += x * f;
        }
    }

    sx  = wave_red_f(sx);   sx2 = wave_red_f(sx2);
    ss  = wave_red_f(ss);   ss2 = wave_red_f(ss2);
    sxs = wave_red_f(sxs);
    sf  = wave_red_f(sf);   sxf = wave_red_f(sxf);

    __shared__ double part[TPB / 64][7];
    const int lane = threadIdx.x & 63;
    const int wave = threadIdx.x >> 6;
    if (lane == 0) {
        part[wave][0] = (double)sx;  part[wave][1] = (double)sx2;
        part[wave][2] = (double)ss;  part[wave][3] = (double)ss2;
        part[wave][4] = (double)sxs;
        part[wave][5] = (double)sf;  part[wave][6] = (double)sxf;
    }
    __syncthreads();
    // Plain stores — no atomics, no pre-zero, no line contention.
    if (threadIdx.x < 7) {
        double t = 0.0;
        #pragma unroll
        for (int wv = 0; wv < TPB / 64; wv++) t += part[wv][threadIdx.x];
        ws1[((size_t)b * BPB + blockIdx.x) * 8 + threadIdx.x] = t;
    }
}

__global__ __launch_bounds__(TPB) void pass2_kernel(
    const float* __restrict__ inp, const float* __restrict__ sal,
    const float* __restrict__ wgt, const double* __restrict__ ws1,
    double* __restrict__ ws2) {
    const int b = blockIdx.y;

    // Every block redundantly reduces this batch's Sx, Ss from ws1 (L2/L3-hot).
    __shared__ float s_invSx, s_invSs;
    {
        double sx = 0.0, ss = 0.0;
        for (int t = threadIdx.x; t < BPB; t += TPB) {
            const double* p = ws1 + ((size_t)b * BPB + t) * 8;
            sx += p[0];
            ss += p[2];
        }
        sx = wave_red_d(sx);
        ss = wave_red_d(ss);
        __shared__ double red[TPB / 64][2];
        const int lane = threadIdx.x & 63;
        const int wave = threadIdx.x >> 6;
        if (lane == 0) { red[wave][0] = sx; red[wave][1] = ss; }
        __syncthreads();
        if (threadIdx.x == 0) {
            double tx = 0.0, ts = 0.0;
            #pragma unroll
            for (int wv = 0; wv < TPB / 64; wv++) { tx += red[wv][0]; ts += red[wv][1]; }
            s_invSx = (float)(1.0 / tx);
            s_invSs = (float)(1.0 / ts);
        }
        __syncthreads();
    }
    const float invSx = s_invSx;
    const float invSs = s_invSs;

    const fvec4* ip = (const fvec4*)(inp + (size_t)b * N);
    const fvec4* sp = (const fvec4*)(sal + (size_t)b * N);
    const fvec4* wp = (const fvec4*)wgt;

    const int g = blockIdx.x * TPB + threadIdx.x;

    fvec4 vi[ITERS], vs[ITERS], vw[ITERS];
    #pragma unroll
    for (int j = 0; j < ITERS; j++) {
        const int i = g + j * TPBATCH;
        vi[j] = ip[i];
        vs[j] = sp[i];
        vw[j] = wp[i];
    }

    float kacc = 0.f;
    #pragma unroll
    for (int j = 0; j < ITERS; j++) {
        #pragma unroll
        for (int k = 0; k < 4; k++) {
            const float xp = vi[j][k] * vw[j][k] * invSx;
            const float yp = vs[j][k] * vw[j][k] * invSs;
            kacc += yp * __logf(yp / (xp + EPS) + EPS);
        }
    }

    kacc = wave_red_f(kacc);
    __shared__ double part[TPB / 64];
    const int lane = threadIdx.x & 63;
    const int wave = threadIdx.x >> 6;
    if (lane == 0) part[wave] = (double)kacc;
    __syncthreads();
    if (threadIdx.x == 0) {
        double t = 0.0;
        #pragma unroll
        for (int wv = 0; wv < TPB / 64; wv++) t += part[wv];
        ws2[(size_t)b * BPB + blockIdx.x] = t;
    }
}

// One block of 128 threads: each thread owns one of the BPB per-block partials.
__global__ __launch_bounds__(128) void finalize_kernel(
    const double* __restrict__ ws1, const double* __restrict__ ws2,
    float* __restrict__ out) {
    const int t    = threadIdx.x;        // 0..127 == BPB
    const int lane = t & 63;
    const int wv   = t >> 6;
    __shared__ double part[2][8];

    double loss = 0.0;
    const double n = (double)N;
    for (int b = 0; b < B; b++) {
        const double* base = ws1 + ((size_t)b * BPB + t) * 8;
        double v[8];
        #pragma unroll
        for (int k = 0; k < 7; k++) v[k] = base[k];
        v[7] = ws2[(size_t)b * BPB + t];
        #pragma unroll
        for (int k = 0; k < 8; k++) {
            double r = wave_red_d(v[k]);
            if (lane == 0) part[wv][k] = r;
        }
        __syncthreads();
        if (t == 0) {
            const double Sx  = part[0][0] + part[1][0];
            const double Sx2 = part[0][1] + part[1][1];
            const double Ss  = part[0][2] + part[1][2];
            const double Ss2 = part[0][3] + part[1][3];
            const double Sxs = part[0][4] + part[1][4];
            const double Sf  = part[0][5] + part[1][5];
            const double Sxf = part[0][6] + part[1][6];
            const double K   = part[0][7] + part[1][7];
            // NSS (ddof=1)
            const double mu  = Sx / n;
            const double var = (Sx2 - Sx * Sx / n) / (n - 1.0);
            const double sd  = sqrt(var);
            const double nss = ((Sxf - mu * Sf) / (sd + (double)EPS)) / (Sf + (double)EPS);
            // CC on x'=x/Sx, y'=s/Ss (sums are exactly 1)
            const double sum_prod = Sxs / (Sx * Ss);
            const double sum_x2   = Sx2 / (Sx * Sx);
            const double sum_y2   = Ss2 / (Ss * Ss);
            const double num = sum_prod - 1.0 / n;
            const double den = sqrt((sum_x2 - 1.0 / n) * (sum_y2 - 1.0 / n));
            const double cc  = num / (den + (double)EPS);
            loss += -0.1 * nss + K - 0.1 * cc;
        }
        __syncthreads();
    }
    if (t == 0) out[0] = (float)(loss / (double)B);
}

extern "C" void kernel_launch(void* const* d_in, const int* in_sizes, int n_in,
                              void* d_out, int out_size, void* d_ws, size_t ws_size,
                              hipStream_t stream) {
    const float* inp = (const float*)d_in[0];
    const float* sal = (const float*)d_in[1];
    const float* fix = (const float*)d_in[2];
    const float* wgt = (const float*)d_in[3];
    float* out = (float*)d_out;
    double* ws1 = (double*)d_ws;
    double* ws2 = ws1 + WS1_DOUBLES;

    dim3 grid(BPB, B);
    pass1_kernel<<<grid, TPB, 0, stream>>>(inp, sal, fix, wgt, ws1);
    pass2_kernel<<<grid, TPB, 0, stream>>>(inp, sal, wgt, ws1, ws2);
    finalize_kernel<<<1, 128, 0, stream>>>(ws1, ws2, out);
}

// Round 4
// 132.920 us; speedup vs baseline: 1.2523x; 1.2523x over previous
//
#include <hip/hip_runtime.h>

#define EPS 1e-7f

constexpr int B   = 16;
constexpr int N   = 512 * 1024;        // elements per batch (C=1)
constexpr int N4  = N / 4;             // float4 per batch = 131072
constexpr int TPB = 256;               // threads per block
constexpr int BPB = 256;               // blocks per batch
constexpr int TPBATCH = TPB * BPB;     // threads covering one batch = 65536
constexpr int ITERS   = N4 / TPBATCH;  // 2 — compile-time, fully unrolled

typedef float fvec4 __attribute__((ext_vector_type(4)));

// ws layout:
//   ws1: [B*BPB][8] doubles  — per-block partials: Sx,Sx2,Ss,Ss2,Sxs,Sf,Sxf,(pad)
//   ws2: [B*BPB]    doubles  — per-block KLD partials
constexpr size_t WS1_DOUBLES = (size_t)B * BPB * 8;

__device__ __forceinline__ float wave_red_f(float v) {
    #pragma unroll
    for (int o = 32; o > 0; o >>= 1) v += __shfl_down(v, o, 64);
    return v;
}
__device__ __forceinline__ double wave_red_d(double v) {
    #pragma unroll
    for (int o = 32; o > 0; o >>= 1) v += __shfl_down(v, o, 64);
    return v;
}

__global__ __launch_bounds__(TPB) void pass1_kernel(
    const float* __restrict__ inp, const float* __restrict__ sal,
    const float* __restrict__ fix, const float* __restrict__ wgt,
    double* __restrict__ ws1, float* __restrict__ out) {
    // Zero the output accumulator once (stream order: visible to finalize).
    if (blockIdx.x == 0 && blockIdx.y == 0 && threadIdx.x == 0) out[0] = 0.0f;

    const int b = blockIdx.y;
    const fvec4* ip = (const fvec4*)(inp + (size_t)b * N);
    const fvec4* sp = (const fvec4*)(sal + (size_t)b * N);
    const fvec4* fp = (const fvec4*)(fix + (size_t)b * N);
    const fvec4* wp = (const fvec4*)wgt;

    const int g = blockIdx.x * TPB + threadIdx.x;   // [0, TPBATCH)

    // Stage loads: 8 x dwordx4 in flight per lane (32 data VGPRs).
    fvec4 vi[ITERS], vs[ITERS], vf[ITERS], vw[ITERS];
    #pragma unroll
    for (int j = 0; j < ITERS; j++) {
        const int i = g + j * TPBATCH;
        vi[j] = ip[i];
        vs[j] = sp[i];
        vf[j] = __builtin_nontemporal_load(&fp[i]);  // fix is read exactly once
        vw[j] = wp[i];
    }

    float sx = 0.f, sx2 = 0.f, ss = 0.f, ss2 = 0.f, sxs = 0.f, sf = 0.f, sxf = 0.f;
    #pragma unroll
    for (int j = 0; j < ITERS; j++) {
        #pragma unroll
        for (int k = 0; k < 4; k++) {
            const float x = vi[j][k] * vw[j][k];
            const float s = vs[j][k] * vw[j][k];
            const float f = vf[j][k] * vw[j][k];
            sx  += x;      sx2 += x * x;
            ss  += s;      ss2 += s * s;
            sxs += x * s;
            sf  += f;      sxf += x * f;
        }
    }

    sx  = wave_red_f(sx);   sx2 = wave_red_f(sx2);
    ss  = wave_red_f(ss);   ss2 = wave_red_f(ss2);
    sxs = wave_red_f(sxs);
    sf  = wave_red_f(sf);   sxf = wave_red_f(sxf);

    __shared__ double part[TPB / 64][7];
    const int lane = threadIdx.x & 63;
    const int wave = threadIdx.x >> 6;
    if (lane == 0) {
        part[wave][0] = (double)sx;  part[wave][1] = (double)sx2;
        part[wave][2] = (double)ss;  part[wave][3] = (double)ss2;
        part[wave][4] = (double)sxs;
        part[wave][5] = (double)sf;  part[wave][6] = (double)sxf;
    }
    __syncthreads();
    if (threadIdx.x < 7) {
        double t = 0.0;
        #pragma unroll
        for (int wv = 0; wv < TPB / 64; wv++) t += part[wv][threadIdx.x];
        ws1[((size_t)b * BPB + blockIdx.x) * 8 + threadIdx.x] = t;
    }
}

__global__ __launch_bounds__(TPB) void pass2_kernel(
    const float* __restrict__ inp, const float* __restrict__ sal,
    const float* __restrict__ wgt, const double* __restrict__ ws1,
    double* __restrict__ ws2) {
    const int b = blockIdx.y;

    // Redundant per-block reduction of this batch's Sx, Ss (L2-hot, overlapped).
    __shared__ float s_invSx, s_invSs;
    {
        const double* p = ws1 + ((size_t)b * BPB + threadIdx.x) * 8;  // TPB == BPB
        double sx = p[0];
        double ss = p[2];
        sx = wave_red_d(sx);
        ss = wave_red_d(ss);
        __shared__ double red[TPB / 64][2];
        const int lane = threadIdx.x & 63;
        const int wave = threadIdx.x >> 6;
        if (lane == 0) { red[wave][0] = sx; red[wave][1] = ss; }
        __syncthreads();
        if (threadIdx.x == 0) {
            double tx = 0.0, ts = 0.0;
            #pragma unroll
            for (int wv = 0; wv < TPB / 64; wv++) { tx += red[wv][0]; ts += red[wv][1]; }
            s_invSx = (float)(1.0 / tx);
            s_invSs = (float)(1.0 / ts);
        }
        __syncthreads();
    }
    const float invSx = s_invSx;
    const float invSs = s_invSs;

    const fvec4* ip = (const fvec4*)(inp + (size_t)b * N);
    const fvec4* sp = (const fvec4*)(sal + (size_t)b * N);
    const fvec4* wp = (const fvec4*)wgt;

    const int g = blockIdx.x * TPB + threadIdx.x;

    fvec4 vi[ITERS], vs[ITERS], vw[ITERS];
    #pragma unroll
    for (int j = 0; j < ITERS; j++) {
        const int i = g + j * TPBATCH;
        vi[j] = ip[i];
        vs[j] = sp[i];
        vw[j] = wp[i];
    }

    float kacc = 0.f;
    #pragma unroll
    for (int j = 0; j < ITERS; j++) {
        #pragma unroll
        for (int k = 0; k < 4; k++) {
            const float xp = vi[j][k] * vw[j][k] * invSx;
            const float yp = vs[j][k] * vw[j][k] * invSs;
            kacc += yp * __logf(yp / (xp + EPS) + EPS);
        }
    }

    kacc = wave_red_f(kacc);
    __shared__ double part[TPB / 64];
    const int lane = threadIdx.x & 63;
    const int wave = threadIdx.x >> 6;
    if (lane == 0) part[wave] = (double)kacc;
    __syncthreads();
    if (threadIdx.x == 0) {
        double t = 0.0;
        #pragma unroll
        for (int wv = 0; wv < TPB / 64; wv++) t += part[wv];
        ws2[(size_t)b * BPB + blockIdx.x] = t;
    }
}

// 16 blocks — one per batch, fully parallel. Each reduces its 256 partials in
// one wave-reduction depth and atomicAdds its scaled contribution to out[0].
__global__ __launch_bounds__(TPB) void finalize_kernel(
    const double* __restrict__ ws1, const double* __restrict__ ws2,
    float* __restrict__ out) {
    const int b    = blockIdx.x;
    const int t    = threadIdx.x;        // 0..255 == BPB
    const int lane = t & 63;
    const int wv   = t >> 6;
    __shared__ double part[TPB / 64][8];

    const double* base = ws1 + ((size_t)b * BPB + t) * 8;
    double v[8];
    #pragma unroll
    for (int k = 0; k < 7; k++) v[k] = base[k];
    v[7] = ws2[(size_t)b * BPB + t];
    #pragma unroll
    for (int k = 0; k < 8; k++) {
        double r = wave_red_d(v[k]);
        if (lane == 0) part[wv][k] = r;
    }
    __syncthreads();
    if (t == 0) {
        double st[8];
        #pragma unroll
        for (int k = 0; k < 8; k++) {
            double acc = 0.0;
            #pragma unroll
            for (int w = 0; w < TPB / 64; w++) acc += part[w][k];
            st[k] = acc;
        }
        const double Sx = st[0], Sx2 = st[1], Ss = st[2], Ss2 = st[3];
        const double Sxs = st[4], Sf = st[5], Sxf = st[6], K = st[7];
        const double n = (double)N;
        // NSS (ddof=1)
        const double mu  = Sx / n;
        const double var = (Sx2 - Sx * Sx / n) / (n - 1.0);
        const double sd  = sqrt(var);
        const double nss = ((Sxf - mu * Sf) / (sd + (double)EPS)) / (Sf + (double)EPS);
        // CC on x'=x/Sx, y'=s/Ss (sums are exactly 1)
        const double sum_prod = Sxs / (Sx * Ss);
        const double sum_x2   = Sx2 / (Sx * Sx);
        const double sum_y2   = Ss2 / (Ss * Ss);
        const double num = sum_prod - 1.0 / n;
        const double den = sqrt((sum_x2 - 1.0 / n) * (sum_y2 - 1.0 / n));
        const double cc  = num / (den + (double)EPS);
        const double contrib = (-0.1 * nss + K - 0.1 * cc) / (double)B;
        atomicAdd(out, (float)contrib);
    }
}

extern "C" void kernel_launch(void* const* d_in, const int* in_sizes, int n_in,
                              void* d_out, int out_size, void* d_ws, size_t ws_size,
                              hipStream_t stream) {
    const float* inp = (const float*)d_in[0];
    const float* sal = (const float*)d_in[1];
    const float* fix = (const float*)d_in[2];
    const float* wgt = (const float*)d_in[3];
    float* out = (float*)d_out;
    double* ws1 = (double*)d_ws;
    double* ws2 = ws1 + WS1_DOUBLES;

    dim3 grid(BPB, B);
    pass1_kernel<<<grid, TPB, 0, stream>>>(inp, sal, fix, wgt, ws1, out);
    pass2_kernel<<<grid, TPB, 0, stream>>>(inp, sal, wgt, ws1, ws2);
    finalize_kernel<<<B, TPB, 0, stream>>>(ws1, ws2, out);
}